// Round 1
// baseline (317.684 us; speedup 1.0000x reference)
//
#include <hip/hip_runtime.h>
#include <hip/hip_bf16.h>

#define N_NODES 1024
#define NCH 64
#define DI 16
#define DODIM 16
#define K3N 16
#define K2N 8
#define K1N 4
#define NEL 10
#define NPAIR 136          // i<=j pairs of 16
#define NEC (NEL*NCH)      // 640

// workspace byte offsets (total ~50.8 MB)
#define WS_OFFS   0
#define WS_LIST   256
#define WS_U1W    8192
#define WS_U2W    663552
#define WS_U3W    6234112

__device__ __forceinline__ float bf16u_to_f(unsigned int u) {
  union { unsigned int i; float f; } v; v.i = u << 16; return v.f;
}
__device__ __forceinline__ unsigned short f_to_bf16u(float f) {
  union { float f; unsigned int i; } v; v.f = f;
  unsigned int x = v.i;
  unsigned int r = (x + 0x7fffu + ((x >> 16) & 1u)) >> 16;
  return (unsigned short)r;
}

// ---------------- kernel 0: bucket nodes by element ----------------
__global__ void k_lists(const int* __restrict__ idx, int* __restrict__ ws_offs,
                        int* __restrict__ ws_list) {
  __shared__ int cnt[NEL];
  __shared__ int base[NEL + 1];
  int t = threadIdx.x;
  if (t < NEL) cnt[t] = 0;
  __syncthreads();
  int e = idx[t];
  int pos = atomicAdd(&cnt[e], 1);
  __syncthreads();
  if (t == 0) {
    int a = 0;
    for (int i = 0; i < NEL; ++i) { base[i] = a; a += cnt[i]; }
    base[NEL] = a;
  }
  __syncthreads();
  ws_list[base[e] + pos] = t;
  if (t <= NEL) ws_offs[t] = base[t];
}

// ---------------- kernel 1: U3w[e,c,o,pair,l] = sum_k U3[o,i,j,l,k]*w3[e,k,c] (bf16) ----
__global__ __launch_bounds__(256) void k_u3w(const float* __restrict__ U3,
                                             const float* __restrict__ w3,
                                             unsigned short* __restrict__ U3w) {
  int o = blockIdx.x & 15;
  int ecb = blockIdx.x >> 4;          // 0..39, 16 (e,c) pairs each (never crosses e)
  int ecbase = ecb * 16;
  int e = ecbase >> 6;
  int cbase = ecbase & 63;
  __shared__ float w3b[16][16];       // [cLocal][k]
  __shared__ int PI[NPAIR], PJ[NPAIR];
  int t = threadIdx.x;
  {
    int cL = t & 15, k = t >> 4;
    w3b[cL][k] = w3[(e * K3N + k) * NCH + cbase + cL];
  }
  if (t < NPAIR) {
    int p = t, i = 0;
    while (p >= 16 - i) { p -= 16 - i; ++i; }
    PI[t] = i; PJ[t] = i + p;
  }
  __syncthreads();
  for (int n = t; n < NPAIR * 16; n += 256) {
    int pair = n >> 4, l = n & 15;
    int i = PI[pair], j = PJ[pair];
    const float* line = U3 + ((size_t)(((o * 16 + i) * 16 + j) * 16 + l)) * 16;
    float a[16];
#pragma unroll
    for (int k = 0; k < 16; ++k) a[k] = line[k];
#pragma unroll
    for (int cL = 0; cL < 16; ++cL) {
      float s = 0.f;
#pragma unroll
      for (int k = 0; k < 16; ++k) s += a[k] * w3b[cL][k];
      int ec = ecbase + cL;
      U3w[((size_t)(ec * 16 + o) * NPAIR + pair) * 16 + l] = f_to_bf16u(s);
    }
  }
}

// ---------------- kernel 1b: U2w[e,c,o,pair], U1w[e,c,o,i] (f32) ----------------
__global__ __launch_bounds__(256) void k_u2w(const float* __restrict__ U2,
                                             const float* __restrict__ U1,
                                             const float* __restrict__ w2,
                                             const float* __restrict__ w1,
                                             float* __restrict__ U2w,
                                             float* __restrict__ U1w) {
  int ec = blockIdx.x;
  int e = ec >> 6, c = ec & 63;
  __shared__ int PI[NPAIR], PJ[NPAIR];
  int t = threadIdx.x;
  if (t < NPAIR) {
    int p = t, i = 0;
    while (p >= 16 - i) { p -= 16 - i; ++i; }
    PI[t] = i; PJ[t] = i + p;
  }
  float w2k[K2N], w1k[K1N];
#pragma unroll
  for (int k = 0; k < K2N; ++k) w2k[k] = w2[(e * K2N + k) * NCH + c];
#pragma unroll
  for (int k = 0; k < K1N; ++k) w1k[k] = w1[(e * K1N + k) * NCH + c];
  __syncthreads();
  for (int n = t; n < 16 * NPAIR; n += 256) {
    int o = n / NPAIR, pair = n - o * NPAIR;
    int i = PI[pair], j = PJ[pair];
    const float* line = U2 + ((o * 16 + i) * 16 + j) * K2N;
    float s = 0.f;
#pragma unroll
    for (int k = 0; k < K2N; ++k) s += line[k] * w2k[k];
    U2w[(size_t)ec * (16 * NPAIR) + n] = s;
  }
  {
    int o = t >> 4, i = t & 15;
    const float* line = U1 + (o * 16 + i) * K1N;
    float s = 0.f;
#pragma unroll
    for (int k = 0; k < K1N; ++k) s += line[k] * w1k[k];
    U1w[ec * 256 + t] = s;
  }
}

// ---------------- kernel 2: per-(e,c) node contraction ----------------
__global__ __launch_bounds__(128) void k_main(const float* __restrict__ x,
                                              const int* __restrict__ offs,
                                              const int* __restrict__ list,
                                              const float* __restrict__ U2w,
                                              const float* __restrict__ U1w,
                                              const unsigned short* __restrict__ U3w,
                                              float* __restrict__ out) {
  int ec = blockIdx.x;
  int e = ec >> 6, c = ec & 63;
  __shared__ float sU3[2][NPAIR * 16];   // double-buffered per-o slice
  __shared__ float sU2[16 * NPAIR];
  __shared__ float sU1[256];
  __shared__ float sX[16][128];
  int t = threadIdx.x;
  for (int n = t; n < 16 * NPAIR; n += 128) sU2[n] = U2w[(size_t)ec * (16 * NPAIR) + n];
  for (int n = t; n < 256; n += 128) sU1[n] = U1w[ec * 256 + n];
  int off = offs[e];
  int nb = offs[e + 1] - off;
  const unsigned short* gU3 = U3w + (size_t)ec * 16 * (NPAIR * 16);

  for (int b0 = 0; b0 < nb; b0 += 128) {
    int myn = b0 + t;
    bool valid = myn < nb;
    int node = valid ? list[off + myn] : 0;
    float xr[16];
    {
      const float4* xp = (const float4*)(x + ((size_t)node * NCH + c) * DI);
      float4 x0 = xp[0], x1 = xp[1], x2 = xp[2], x3 = xp[3];
      xr[0] = x0.x; xr[1] = x0.y; xr[2] = x0.z; xr[3] = x0.w;
      xr[4] = x1.x; xr[5] = x1.y; xr[6] = x1.z; xr[7] = x1.w;
      xr[8] = x2.x; xr[9] = x2.y; xr[10] = x2.z; xr[11] = x2.w;
      xr[12] = x3.x; xr[13] = x3.y; xr[14] = x3.z; xr[15] = x3.w;
    }
#pragma unroll
    for (int l = 0; l < 16; ++l) sX[l][t] = xr[l];
    // prologue: stage o=0
    for (int n = t; n < NPAIR * 16; n += 128) sU3[0][n] = bf16u_to_f(gU3[n]);
    __syncthreads();

#pragma unroll 1
    for (int o = 0; o < 16; ++o) {
      // issue next-o global loads early (hide under compute)
      unsigned int sreg[9];
      if (o < 15) {
        const unsigned int* g = (const unsigned int*)(gU3 + (size_t)(o + 1) * (NPAIR * 16));
#pragma unroll
        for (int r = 0; r < 8; ++r) sreg[r] = g[t + 128 * r];
        if (t < 64) sreg[8] = g[t + 1024];
      }
      const float* u3 = sU3[o & 1];
      const float* u2o = sU2 + o * NPAIR;
      float acc = 0.f;
      for (int j = 0; j < 16; ++j) {
        float xj = sX[j][t];
#pragma unroll
        for (int i = 0; i < 16; ++i) {
          if (i <= j) {
            const int pb = 16 * i - (i * (i + 1)) / 2;   // pair base for row i
            float s = u2o[pb + j];
            const float* ln = u3 + (pb + j) * 16;
#pragma unroll
            for (int l = 0; l < 16; ++l) s += ln[l] * xr[l];
            float w = xr[i] * xj;
            if (i != j) w += w;        // (2 - delta_ij)
            acc += s * w;
          }
        }
      }
#pragma unroll
      for (int i = 0; i < 16; ++i) acc += sU1[o * 16 + i] * xr[i];
      if (valid) out[((size_t)node * NCH + c) * DODIM + o] = acc;
      // write next-o staging into the other buffer (safe: nobody reads it this o)
      if (o < 15) {
        float2* dst = (float2*)sU3[(o + 1) & 1];
#pragma unroll
        for (int r = 0; r < 8; ++r) {
          unsigned int v = sreg[r];
          dst[t + 128 * r] = make_float2(bf16u_to_f(v & 0xffffu), bf16u_to_f(v >> 16));
        }
        if (t < 64) {
          unsigned int v = sreg[8];
          dst[t + 1024] = make_float2(bf16u_to_f(v & 0xffffu), bf16u_to_f(v >> 16));
        }
      }
      __syncthreads();
    }
  }
}

extern "C" void kernel_launch(void* const* d_in, const int* in_sizes, int n_in,
                              void* d_out, int out_size, void* d_ws, size_t ws_size,
                              hipStream_t stream) {
  (void)in_sizes; (void)n_in; (void)out_size; (void)ws_size;
  const float* x   = (const float*)d_in[0];
  const int*   idx = (const int*)d_in[1];
  const float* w1  = (const float*)d_in[2];
  const float* w2  = (const float*)d_in[3];
  const float* w3  = (const float*)d_in[4];
  const float* U1  = (const float*)d_in[5];
  const float* U2  = (const float*)d_in[6];
  const float* U3  = (const float*)d_in[7];
  float* out = (float*)d_out;
  char* ws = (char*)d_ws;
  int* ws_offs = (int*)(ws + WS_OFFS);
  int* ws_list = (int*)(ws + WS_LIST);
  float* U1w = (float*)(ws + WS_U1W);
  float* U2w = (float*)(ws + WS_U2W);
  unsigned short* U3w = (unsigned short*)(ws + WS_U3W);

  hipLaunchKernelGGL(k_lists, dim3(1), dim3(1024), 0, stream, idx, ws_offs, ws_list);
  hipLaunchKernelGGL(k_u3w, dim3(640), dim3(256), 0, stream, U3, w3, U3w);
  hipLaunchKernelGGL(k_u2w, dim3(640), dim3(256), 0, stream, U2, U1, w2, w1, U2w, U1w);
  hipLaunchKernelGGL(k_main, dim3(640), dim3(128), 0, stream, x, ws_offs, ws_list,
                     U2w, U1w, U3w, out);
}

// Round 2
// 112.553 us; speedup vs baseline: 2.8225x; 2.8225x over previous
//
#include <hip/hip_runtime.h>
#include <hip/hip_bf16.h>

#define NCH 64
#define NEL 10
#define NPAIR 136
#define K_B  2336            // 73 * 32 : 2176 cubic + 136 quad + 16 linear + 8 pad
#define K_PAD 2344           // LDS row pad: stride 4688 B == 1172 words == 20 mod 32 (2-way, free)

#define WS_OFFS  0
#define WS_LIST  1024
#define WS_WFULL 8192        // 640 * 16 * 2336 * 2B = 47.84 MB

typedef __attribute__((ext_vector_type(8))) short  short8v;
typedef __attribute__((ext_vector_type(4))) float  float4v;
typedef __attribute__((ext_vector_type(4))) int    int4v;

__host__ __device__ constexpr int PIc(int p) { int i = 0; while (p >= 16 - i) { p -= 16 - i; ++i; } return i; }
__host__ __device__ constexpr int PJc(int p) { int i = 0; while (p >= 16 - i) { p -= 16 - i; ++i; } return i + p; }

__device__ __forceinline__ unsigned short f_to_bf16u(float f) {
  union { float f; unsigned int i; } v; v.f = f;
  unsigned int x = v.i;
  unsigned int r = (x + 0x7fffu + ((x >> 16) & 1u)) >> 16;
  return (unsigned short)r;
}

// ---------------- kernel 0: bucket nodes by element ----------------
__global__ void k_lists(const int* __restrict__ idx, int* __restrict__ ws_offs,
                        int* __restrict__ ws_list) {
  __shared__ int cnt[NEL];
  __shared__ int base[NEL + 1];
  int t = threadIdx.x;
  if (t < NEL) cnt[t] = 0;
  __syncthreads();
  int e = idx[t];
  int pos = atomicAdd(&cnt[e], 1);
  __syncthreads();
  if (t == 0) {
    int a = 0;
    for (int i = 0; i < NEL; ++i) { base[i] = a; a += cnt[i]; }
    base[NEL] = a;
  }
  __syncthreads();
  ws_list[base[e] + pos] = t;
  if (t <= NEL) ws_offs[t] = base[t];
}

// ------- kernel 1: cubic region of Wfull: q = pair*16 + l, scaled by (2-delta_ij) -------
__global__ __launch_bounds__(256) void k_w3(const float* __restrict__ U3,
                                            const float* __restrict__ w3,
                                            unsigned short* __restrict__ Wfull) {
  int o = blockIdx.x & 15;
  int ecb = blockIdx.x >> 4;          // 40 blocks of 16 (e,c) pairs (never crosses e)
  int ecbase = ecb * 16;
  int e = ecbase >> 6;
  int cbase = ecbase & 63;
  __shared__ float w3b[16][16];       // [cLocal][k]
  __shared__ int PI[NPAIR], PJ[NPAIR];
  int t = threadIdx.x;
  {
    int cL = t & 15, k = t >> 4;
    w3b[cL][k] = w3[(e * 16 + k) * NCH + cbase + cL];
  }
  if (t < NPAIR) {
    int p = t, i = 0;
    while (p >= 16 - i) { p -= 16 - i; ++i; }
    PI[t] = i; PJ[t] = i + p;
  }
  __syncthreads();
  for (int n = t; n < NPAIR * 16; n += 256) {
    int pair = n >> 4, l = n & 15;
    int i = PI[pair], j = PJ[pair];
    float sc = (i == j) ? 1.f : 2.f;
    const float* line = U3 + ((size_t)(((o * 16 + i) * 16 + j) * 16 + l)) * 16;
    float a[16];
#pragma unroll
    for (int k = 0; k < 16; ++k) a[k] = line[k];
#pragma unroll
    for (int cL = 0; cL < 16; ++cL) {
      float s = 0.f;
#pragma unroll
      for (int k = 0; k < 16; ++k) s += a[k] * w3b[cL][k];
      Wfull[((size_t)(ecbase + cL) * 16 + o) * K_B + pair * 16 + l] = f_to_bf16u(sc * s);
    }
  }
}

// ------- kernel 2: quad / linear / pad regions of Wfull (q in [2176, 2336)) -------
__global__ __launch_bounds__(256) void k_w21(const float* __restrict__ U2,
                                             const float* __restrict__ U1,
                                             const float* __restrict__ w2,
                                             const float* __restrict__ w1,
                                             unsigned short* __restrict__ Wfull) {
  int ec = blockIdx.x;
  int e = ec >> 6, c = ec & 63;
  int t = threadIdx.x;
  float w2k[8], w1k[4];
#pragma unroll
  for (int k = 0; k < 8; ++k) w2k[k] = w2[(e * 8 + k) * NCH + c];
#pragma unroll
  for (int k = 0; k < 4; ++k) w1k[k] = w1[(e * 4 + k) * NCH + c];
  for (int n = t; n < 16 * 160; n += 256) {
    int o = n / 160, r = n - o * 160;
    float val = 0.f;
    if (r < 136) {
      int p = r, i = 0;
      while (p >= 16 - i) { p -= 16 - i; ++i; }
      int j = i + p;
      float sc = (i == j) ? 1.f : 2.f;
      const float* line = U2 + ((o * 16 + i) * 16 + j) * 8;
      float s = 0.f;
#pragma unroll
      for (int k = 0; k < 8; ++k) s += line[k] * w2k[k];
      val = sc * s;
    } else if (r < 152) {
      int i = r - 136;
      const float* line = U1 + (o * 16 + i) * 4;
      float s = 0.f;
#pragma unroll
      for (int k = 0; k < 4; ++k) s += line[k] * w1k[k];
      val = s;
    }
    Wfull[((size_t)ec * 16 + o) * K_B + 2176 + r] = f_to_bf16u(val);
  }
}

// ---------------- kernel 3: MFMA main — per (e,c), nodes x monomials GEMM ----------------
#define CUBIC_STEP(KK, ACC) { \
  constexpr int i0 = PIc(2 * (KK)), j0 = PJc(2 * (KK)); \
  constexpr int i1 = PIc(2 * (KK) + 1), j1 = PJc(2 * (KK) + 1); \
  float xxA = xr[i0] * xr[j0]; \
  float xxB = xr[i1] * xr[j1]; \
  float xx = selOdd ? xxB : xxA; \
  int b0, b1, b2, b3; \
  asm("v_cvt_pk_bf16_f32 %0, %1, %2" : "=v"(b0) : "v"(xx * xs[0]), "v"(xx * xs[1])); \
  asm("v_cvt_pk_bf16_f32 %0, %1, %2" : "=v"(b1) : "v"(xx * xs[2]), "v"(xx * xs[3])); \
  asm("v_cvt_pk_bf16_f32 %0, %1, %2" : "=v"(b2) : "v"(xx * xs[4]), "v"(xx * xs[5])); \
  asm("v_cvt_pk_bf16_f32 %0, %1, %2" : "=v"(b3) : "v"(xx * xs[6]), "v"(xx * xs[7])); \
  int4v ai = {b0, b1, b2, b3}; \
  short8v av = __builtin_bit_cast(short8v, ai); \
  short8v bv = *(const short8v*)(bp + (KK) * 32); \
  ACC = __builtin_amdgcn_mfma_f32_16x16x32_bf16(av, bv, ACC, 0, 0, 0); \
}

#define TAIL_STEP(KK, ACC) { \
  float mv[8]; \
  _Pragma("unroll") \
  for (int j = 0; j < 8; ++j) { \
    int spec = sT[(KK) * 32 - 2176 + g * 8 + j]; \
    mv[j] = sX[w][rc][spec & 31] * sX[w][rc][(spec >> 8) & 31]; \
  } \
  int b0, b1, b2, b3; \
  asm("v_cvt_pk_bf16_f32 %0, %1, %2" : "=v"(b0) : "v"(mv[0]), "v"(mv[1])); \
  asm("v_cvt_pk_bf16_f32 %0, %1, %2" : "=v"(b1) : "v"(mv[2]), "v"(mv[3])); \
  asm("v_cvt_pk_bf16_f32 %0, %1, %2" : "=v"(b2) : "v"(mv[4]), "v"(mv[5])); \
  asm("v_cvt_pk_bf16_f32 %0, %1, %2" : "=v"(b3) : "v"(mv[6]), "v"(mv[7])); \
  int4v ai = {b0, b1, b2, b3}; \
  short8v av = __builtin_bit_cast(short8v, ai); \
  short8v bv = *(const short8v*)(bp + (KK) * 32); \
  ACC = __builtin_amdgcn_mfma_f32_16x16x32_bf16(av, bv, ACC, 0, 0, 0); \
}

#define C2(K)  CUBIC_STEP(K, acc0) CUBIC_STEP((K) + 1, acc1)
#define C8(K)  C2(K) C2((K) + 2) C2((K) + 4) C2((K) + 6)
#define C32(K) C8(K) C8((K) + 8) C8((K) + 16) C8((K) + 24)

__global__ __launch_bounds__(256, 2) void k_main(const float* __restrict__ x,
                                                 const int* __restrict__ offs,
                                                 const int* __restrict__ list,
                                                 const unsigned short* __restrict__ Wfull,
                                                 float* __restrict__ out) {
  int ec = blockIdx.x;
  int e = ec >> 6, c = ec & 63;
  __shared__ unsigned short sB[16 * K_PAD];   // 75008 B, padded rows
  __shared__ float sX[4][16][18];             // per-wave row x values (+1.0, +0.0 slots)
  __shared__ int sT[160];                     // tail monomial spec (i | j<<8)
  __shared__ int sNode[4][16];                // per-wave tile node ids (-1 invalid)
  int t = threadIdx.x;

  // stage B: Wfull[ec] -> padded LDS rows (16 o-rows, 292 x 16B chunks each)
  {
    const unsigned short* gB = Wfull + (size_t)ec * (16 * K_B);
    int oy = t >> 4, tx = t & 15;
    for (int n = tx; n < 292; n += 16) {
      *(uint4*)(&sB[oy * K_PAD + n * 8]) = *(const uint4*)(gB + oy * K_B + n * 8);
    }
  }
  // tail spec table
  for (int r = t; r < 160; r += 256) {
    int i, j;
    if (r < 136) {
      int p = r, ii = 0;
      while (p >= 16 - ii) { p -= 16 - ii; ++ii; }
      i = ii; j = ii + p;
    } else if (r < 152) { i = r - 136; j = 16; }
    else { i = 17; j = 17; }
    sT[r] = i | (j << 8);
  }
  __syncthreads();

  int off = offs[e], nb = offs[e + 1] - off;
  int nt = (nb + 15) >> 4;
  int w = t >> 6, lane = t & 63;
  int rc = lane & 15;          // A-row (node) for input frags; N-col (o) for B/D
  int g = lane >> 4;
  bool selOdd = (lane >= 32);
  bool selHi = (g & 1);
  const unsigned short* bp = sB + rc * K_PAD + g * 8;

  for (int tile = w; tile < nt; tile += 4) {
    int m = tile * 16 + rc;
    int node = list[off + (m < nb ? m : nb - 1)];
    float xr[16];
    {
      const float4* xp = (const float4*)(x + ((size_t)node * NCH + c) * 16);
      float4 q0 = xp[0], q1 = xp[1], q2 = xp[2], q3 = xp[3];
      xr[0] = q0.x; xr[1] = q0.y; xr[2] = q0.z; xr[3] = q0.w;
      xr[4] = q1.x; xr[5] = q1.y; xr[6] = q1.z; xr[7] = q1.w;
      xr[8] = q2.x; xr[9] = q2.y; xr[10] = q2.z; xr[11] = q2.w;
      xr[12] = q3.x; xr[13] = q3.y; xr[14] = q3.z; xr[15] = q3.w;
    }
    float xs[8];
#pragma unroll
    for (int j = 0; j < 8; ++j) xs[j] = selHi ? xr[8 + j] : xr[j];
    if (g == 0) {               // lanes 0..15 publish their row for the tail steps
#pragma unroll
      for (int l = 0; l < 16; ++l) sX[w][rc][l] = xr[l];
      sX[w][rc][16] = 1.f; sX[w][rc][17] = 0.f;
      sNode[w][rc] = (m < nb) ? node : -1;
    }

    float4v acc0 = {0.f, 0.f, 0.f, 0.f};
    float4v acc1 = {0.f, 0.f, 0.f, 0.f};
    C32(0) C32(32) C2(64) C2(66)          // 68 cubic K-steps
    TAIL_STEP(68, acc0) TAIL_STEP(69, acc1) TAIL_STEP(70, acc0)
    TAIL_STEP(71, acc1) TAIL_STEP(72, acc0)
    float4v accs = acc0 + acc1;

#pragma unroll
    for (int r2 = 0; r2 < 4; ++r2) {
      int nd = sNode[w][g * 4 + r2];
      if (nd >= 0) out[((size_t)nd * NCH + c) * 16 + rc] = accs[r2];
    }
  }
}

extern "C" void kernel_launch(void* const* d_in, const int* in_sizes, int n_in,
                              void* d_out, int out_size, void* d_ws, size_t ws_size,
                              hipStream_t stream) {
  (void)in_sizes; (void)n_in; (void)out_size; (void)ws_size;
  const float* x   = (const float*)d_in[0];
  const int*   idx = (const int*)d_in[1];
  const float* w1  = (const float*)d_in[2];
  const float* w2  = (const float*)d_in[3];
  const float* w3  = (const float*)d_in[4];
  const float* U1  = (const float*)d_in[5];
  const float* U2  = (const float*)d_in[6];
  const float* U3  = (const float*)d_in[7];
  float* out = (float*)d_out;
  char* ws = (char*)d_ws;
  int* ws_offs = (int*)(ws + WS_OFFS);
  int* ws_list = (int*)(ws + WS_LIST);
  unsigned short* Wfull = (unsigned short*)(ws + WS_WFULL);

  hipLaunchKernelGGL(k_lists, dim3(1), dim3(1024), 0, stream, idx, ws_offs, ws_list);
  hipLaunchKernelGGL(k_w3, dim3(640), dim3(256), 0, stream, U3, w3, Wfull);
  hipLaunchKernelGGL(k_w21, dim3(640), dim3(256), 0, stream, U2, U1, w2, w1, Wfull);
  hipLaunchKernelGGL(k_main, dim3(640), dim3(256), 0, stream, x, ws_offs, ws_list,
                     Wfull, out);
}